// Round 1
// baseline (202.119 us; speedup 1.0000x reference)
//
#include <hip/hip_runtime.h>
#include <hip/hip_bf16.h>
#include <math.h>

#define DEVFN __device__ __forceinline__

typedef __attribute__((ext_vector_type(8))) __bf16 bf16x8;
typedef __attribute__((ext_vector_type(8))) short s16x8;
typedef __attribute__((ext_vector_type(4))) float f32x4;
typedef __attribute__((ext_vector_type(4))) unsigned int u32x4;

constexpr int Tt    = 2048;
constexpr int INt   = 128;
constexpr int Ht    = 256;
constexpr int OUTt  = 8;
constexpr int TT    = 16;           // time tile
constexpr int NTILE = Tt / TT;      // 128

union Frag {
  s16x8 s;
  bf16x8 b;
  u32x4 u;
};

DEVFN unsigned short f2bf(float f) {
  unsigned int u = __builtin_bit_cast(unsigned int, f);
  u += 0x7fffu + ((u >> 16) & 1u);   // round-to-nearest-even
  return (unsigned short)(u >> 16);
}

DEVFN unsigned int pack2(float lo, float hi) {
  return (unsigned int)f2bf(lo) | ((unsigned int)f2bf(hi) << 16);
}

__global__ __launch_bounds__(256, 1) void sfnn_fused(
    const float* __restrict__ x, const float* __restrict__ Wb,
    const float* __restrict__ bb, const float* __restrict__ Wo,
    const float* __restrict__ bo, const float* __restrict__ tau_m,
    const float* __restrict__ tau_n, float* __restrict__ out)
{
  const int b    = blockIdx.x;
  const int tid  = threadIdx.x;
  const int lane = tid & 63;
  const int w    = tid >> 6;          // wave id, owns h in [64w, 64w+64)

  __shared__ __align__(16) unsigned char XldsB[2][TT * INt * 2]; // bf16, swizzled
  __shared__ __align__(16) unsigned char DldsB[TT * Ht * 4];     // f32, swizzled
  __shared__ __align__(16) unsigned char MldsB[TT * Ht * 2];     // bf16, swizzled
  __shared__ float Plds[4][TT][16];                              // proj partials

  // per-channel params (thread h = tid)
  const float beta  = 1.f / (1.f + expf(-tau_n[tid]));
  const float alpha = 1.f / (1.f + expf(-tau_m[tid]));
  const float omb   = 1.f - beta;
  const float oma   = 1.f - alpha;
  const float bbh   = bb[tid];
  const float bo_j  = ((tid & 15) < OUTt) ? bo[tid & 15] : 0.f;

  const int l16 = lane & 15;
  const int lhi = lane >> 4;

  // ---- branch-weight fragments (B operand), held in registers all kernel ----
  // W[i][h] = Wb[n=h/64][i][s=h%64]; wave w covers h in [64w,64w+64) so n == w.
  Frag Wf[4][4];                      // [n-tile][k-step]
  #pragma unroll
  for (int nt = 0; nt < 4; ++nt) {
    const int s = nt * 16 + l16;
    #pragma unroll
    for (int ks = 0; ks < 4; ++ks) {
      #pragma unroll
      for (int j = 0; j < 8; ++j) {
        const int i = ks * 32 + lhi * 8 + j;
        Wf[nt][ks].s[j] = (short)f2bf(Wb[w * 8192 + i * 64 + s]);
      }
    }
  }
  // ---- output-weight fragments (B operand of projection, cols >=8 zero) ----
  Frag WoF[2];
  #pragma unroll
  for (int ks = 0; ks < 2; ++ks) {
    #pragma unroll
    for (int j = 0; j < 8; ++j) {
      const int kk = w * 64 + ks * 32 + lhi * 8 + j;
      const float v = (l16 < OUTt) ? Wo[kk * OUTt + l16] : 0.f;
      WoF[ks].s[j] = (short)f2bf(v);
    }
  }

  const float* xb   = x   + (size_t)b * Tt * INt;
  float*       outb = out + (size_t)b * Tt * OUTt;

  const int tl = tid >> 4;            // staging row (time within tile)
  const int i0 = (tid & 15) * 8;      // staging col start (IN index)

  // prologue: stage tile 0
  {
    const float4 va = *(const float4*)(xb + tl * INt + i0);
    const float4 vb = *(const float4*)(xb + tl * INt + i0 + 4);
    u32x4 pk;
    pk.x = pack2(va.x, va.y); pk.y = pack2(va.z, va.w);
    pk.z = pack2(vb.x, vb.y); pk.w = pack2(vb.z, vb.w);
    *(u32x4*)(&XldsB[0][tl * 256 + ((i0 * 2) ^ ((tl & 7) << 4))]) = pk;
  }
  __syncthreads();

  float c_s = 0.f, m_s = 0.f;

  for (int kt = 0; kt < NTILE; ++kt) {
    const int  cur      = kt & 1;
    const bool havenext = (kt + 1 < NTILE);

    // issue next-tile global loads early (latency hides under compute)
    float4 va, vb;
    if (havenext) {
      const float* src = xb + (size_t)(kt + 1) * TT * INt + tl * INt + i0;
      va = *(const float4*)src;
      vb = *(const float4*)(src + 4);
    }

    // ---- D-GEMM: this wave's 16(t) x 64(h) slice, K=128 ----
    Frag a[4];
    #pragma unroll
    for (int ks = 0; ks < 4; ++ks) {
      const int k0 = ks * 32 + lhi * 8;
      a[ks].u = *(const u32x4*)(&XldsB[cur][l16 * 256 + ((k0 * 2) ^ ((l16 & 7) << 4))]);
    }
    f32x4 dacc[4];
    #pragma unroll
    for (int nt = 0; nt < 4; ++nt) {
      dacc[nt] = f32x4{0.f, 0.f, 0.f, 0.f};
      #pragma unroll
      for (int ks = 0; ks < 4; ++ks)
        dacc[nt] = __builtin_amdgcn_mfma_f32_16x16x32_bf16(
            a[ks].b, Wf[nt][ks].b, dacc[nt], 0, 0, 0);
    }
    // C/D layout: col = lane&15, row = (lane>>4)*4 + r  (HW-verified mapping)
    #pragma unroll
    for (int nt = 0; nt < 4; ++nt) {
      const int hcol = w * 64 + nt * 16 + l16;
      #pragma unroll
      for (int r = 0; r < 4; ++r) {
        const int tr = lhi * 4 + r;
        *(float*)(&DldsB[tr * 1024 + ((hcol * 4) ^ (((tr >> 2) & 3) << 4))]) = dacc[nt][r];
      }
    }

    // ---- dual-EMA scan, thread h = tid, state in registers ----
    #pragma unroll
    for (int t = 0; t < TT; ++t) {
      const float d = *(const float*)(&DldsB[t * 1024 + ((tid * 4) ^ (((t >> 2) & 3) << 4))]) + bbh;
      c_s = fmaf(beta, c_s, omb * d);
      m_s = fmaf(alpha, m_s, oma * c_s);
      *(unsigned short*)(&MldsB[t * 512 + ((tid * 2) ^ ((t & 7) << 4))]) = f2bf(m_s);
    }

    // ---- projection partial: M[:, 64w:64w+64] @ Wo[64w:64w+64, :16] ----
    f32x4 p = f32x4{0.f, 0.f, 0.f, 0.f};
    #pragma unroll
    for (int ks = 0; ks < 2; ++ks) {
      const int k0 = w * 64 + ks * 32 + lhi * 8;
      Frag ma;
      ma.u = *(const u32x4*)(&MldsB[l16 * 512 + ((k0 * 2) ^ ((l16 & 7) << 4))]);
      p = __builtin_amdgcn_mfma_f32_16x16x32_bf16(ma.b, WoF[ks].b, p, 0, 0, 0);
    }
    #pragma unroll
    for (int r = 0; r < 4; ++r)
      Plds[w][lhi * 4 + r][l16] = p[r];

    // ---- write prefetched x tile into the other buffer ----
    if (havenext) {
      u32x4 pk;
      pk.x = pack2(va.x, va.y); pk.y = pack2(va.z, va.w);
      pk.z = pack2(vb.x, vb.y); pk.w = pack2(vb.z, vb.w);
      *(u32x4*)(&XldsB[cur ^ 1][tl * 256 + ((i0 * 2) ^ ((tl & 7) << 4))]) = pk;
    }

    __syncthreads();

    // ---- cross-wave reduce + bias + sigmoid + coalesced store ----
    {
      const int trow = tid >> 4, j = tid & 15;
      if (j < OUTt) {
        const float sum = Plds[0][trow][j] + Plds[1][trow][j] +
                          Plds[2][trow][j] + Plds[3][trow][j] + bo_j;
        outb[(size_t)(kt * TT + trow) * OUTt + j] = 1.f / (1.f + __expf(-sum));
      }
    }
    __syncthreads();
  }
}

extern "C" void kernel_launch(void* const* d_in, const int* in_sizes, int n_in,
                              void* d_out, int out_size, void* d_ws, size_t ws_size,
                              hipStream_t stream) {
  const float* x     = (const float*)d_in[0];
  const float* Wb    = (const float*)d_in[1];
  const float* bb    = (const float*)d_in[2];
  const float* Wo    = (const float*)d_in[3];
  const float* bo    = (const float*)d_in[4];
  const float* tau_m = (const float*)d_in[5];
  const float* tau_n = (const float*)d_in[6];
  float* out = (float*)d_out;

  sfnn_fused<<<dim3(256), dim3(256), 0, stream>>>(x, Wb, bb, Wo, bo, tau_m, tau_n, out);
}

// Round 2
// 138.980 us; speedup vs baseline: 1.4543x; 1.4543x over previous
//
#include <hip/hip_runtime.h>
#include <hip/hip_bf16.h>
#include <math.h>

#define DEVFN __device__ __forceinline__

typedef __attribute__((ext_vector_type(8))) __bf16 bf16x8;
typedef __attribute__((ext_vector_type(8))) short s16x8;
typedef __attribute__((ext_vector_type(4))) float f32x4;
typedef __attribute__((ext_vector_type(4))) unsigned int u32x4;

constexpr int Tt    = 2048;
constexpr int INt   = 128;
constexpr int Ht    = 256;
constexpr int OUTt  = 8;
constexpr int TT    = 64;           // time tile
constexpr int NTILE = Tt / TT;      // 32

union Frag {
  s16x8 s;
  bf16x8 b;
  u32x4 u;
};

DEVFN unsigned short f2bf(float f) {
  unsigned int u = __builtin_bit_cast(unsigned int, f);
  u += 0x7fffu + ((u >> 16) & 1u);   // round-to-nearest-even
  return (unsigned short)(u >> 16);
}

DEVFN unsigned int pack2(float lo, float hi) {
  return (unsigned int)f2bf(lo) | ((unsigned int)f2bf(hi) << 16);
}

__global__ __launch_bounds__(1024, 4) void sfnn_fused(
    const float* __restrict__ x, const float* __restrict__ Wb,
    const float* __restrict__ bb, const float* __restrict__ Wo,
    const float* __restrict__ bo, const float* __restrict__ tau_m,
    const float* __restrict__ tau_n, float* __restrict__ out)
{
  const int b    = blockIdx.x;
  const int tid  = threadIdx.x;
  const int lane = tid & 63;
  const int w    = tid >> 6;          // wave id 0..15
  const int l16  = lane & 15;
  const int lhi  = lane >> 4;

  // D-GEMM wave geometry: 64t x 256h tile, each wave a 32x32 patch
  const int tg = w >> 3;              // 0..1  -> t rows [32tg, 32tg+32)
  const int hg = w & 7;               // 0..7  -> h cols [32hg, 32hg+32)
  // projection wave geometry: each wave 16t x (64-wide k slice)
  const int tp = w >> 2;              // 0..3
  const int hp = w & 3;               // 0..3

  __shared__ __align__(16) unsigned char Xb[2][TT * INt * 2];   // bf16, swizzled
  __shared__ __align__(16) float          Df[TT * Ht];          // f32, swizzled
  __shared__ __align__(16) unsigned char  Mb[TT * Ht * 2];      // bf16, swizzled
  __shared__ float Plds[4][4][16][16];                          // [tp][hp][t16][j]

  // per-channel scan params (threads 0..255 use channel h = tid)
  const int   hch   = tid & 255;
  const float beta  = 1.f / (1.f + expf(-tau_n[hch]));
  const float alpha = 1.f / (1.f + expf(-tau_m[hch]));
  const float omb   = 1.f - beta;
  const float oma   = 1.f - alpha;
  const float bbh   = bb[hch];
  const float bo_j  = bo[tid & 7];

  // ---- branch-weight fragments (B operand of D-GEMM), registers all kernel ----
  Frag Wf[2][4];                      // [nh 16-col half][k-step]
  #pragma unroll
  for (int nh = 0; nh < 2; ++nh) {
    const int h = 32 * hg + 16 * nh + l16;
    const int n = h >> 6, s = h & 63;
    #pragma unroll
    for (int ks = 0; ks < 4; ++ks) {
      #pragma unroll
      for (int j = 0; j < 8; ++j) {
        const int i = 32 * ks + 8 * lhi + j;
        Wf[nh][ks].s[j] = (short)f2bf(Wb[(n * 128 + i) * 64 + s]);
      }
    }
  }
  // ---- output-weight fragments (B operand of projection, cols >=8 zero) ----
  Frag WoF[2];
  #pragma unroll
  for (int ks = 0; ks < 2; ++ks) {
    #pragma unroll
    for (int j = 0; j < 8; ++j) {
      const int kk = 64 * hp + 32 * ks + 8 * lhi + j;
      const float v = (l16 < OUTt) ? Wo[kk * OUTt + l16] : 0.f;
      WoF[ks].s[j] = (short)f2bf(v);
    }
  }

  const float* xb   = x   + (size_t)b * Tt * INt;
  float*       outb = out + (size_t)b * Tt * OUTt;

  const int tl = tid >> 4;            // staging row 0..63
  const int i0 = (tid & 15) * 8;      // staging col start

  // prologue: stage tile 0
  {
    const float4 va = *(const float4*)(xb + tl * INt + i0);
    const float4 vb = *(const float4*)(xb + tl * INt + i0 + 4);
    u32x4 pk;
    pk.x = pack2(va.x, va.y); pk.y = pack2(va.z, va.w);
    pk.z = pack2(vb.x, vb.y); pk.w = pack2(vb.z, vb.w);
    *(u32x4*)(&Xb[0][tl * 256 + ((i0 * 2) ^ ((tl & 7) << 4))]) = pk;
  }
  __syncthreads();

  float c_s = 0.f, m_s = 0.f;

  for (int kt = 0; kt < NTILE; ++kt) {
    const int  cur      = kt & 1;
    const bool havenext = (kt + 1 < NTILE);

    // issue next-tile global loads early
    float4 va, vb;
    if (havenext) {
      const float* src = xb + (size_t)(kt + 1) * TT * INt + tl * INt + i0;
      va = *(const float4*)src;
      vb = *(const float4*)(src + 4);
    }

    // ---- D-GEMM: wave computes D[32tg..+32)[32hg..+32), K=128 ----
    f32x4 dacc[2][2];
    #pragma unroll
    for (int th = 0; th < 2; ++th) {
      Frag a[4];
      const int row = 32 * tg + 16 * th + l16;
      #pragma unroll
      for (int ks = 0; ks < 4; ++ks) {
        const int k0 = (32 * ks + 8 * lhi) * 2;
        a[ks].u = *(const u32x4*)(&Xb[cur][row * 256 + (k0 ^ ((row & 7) << 4))]);
      }
      #pragma unroll
      for (int nh = 0; nh < 2; ++nh) {
        dacc[th][nh] = f32x4{0.f, 0.f, 0.f, 0.f};
        #pragma unroll
        for (int ks = 0; ks < 4; ++ks)
          dacc[th][nh] = __builtin_amdgcn_mfma_f32_16x16x32_bf16(
              a[ks].b, Wf[nh][ks].b, dacc[th][nh], 0, 0, 0);
      }
    }
    // C/D: col = l16, row = lhi*4 + r
    #pragma unroll
    for (int th = 0; th < 2; ++th)
      #pragma unroll
      for (int nh = 0; nh < 2; ++nh) {
        const int h = 32 * hg + 16 * nh + l16;
        #pragma unroll
        for (int r = 0; r < 4; ++r) {
          const int t = 32 * tg + 16 * th + 4 * lhi + r;
          Df[t * 256 + (h ^ (((t >> 2) & 3) << 4))] = dacc[th][nh][r];
        }
      }

    __syncthreads();  // B1: D complete, Xb[cur] reads complete

    // ---- all threads: write staged x into other buffer ----
    if (havenext) {
      u32x4 pk;
      pk.x = pack2(va.x, va.y); pk.y = pack2(va.z, va.w);
      pk.z = pack2(vb.x, vb.y); pk.w = pack2(vb.z, vb.w);
      *(u32x4*)(&Xb[cur ^ 1][tl * 256 + ((i0 * 2) ^ ((tl & 7) << 4))]) = pk;
    }

    // ---- scan: threads 0..255, channel h = tid, 64 serial steps ----
    if (tid < 256) {
      #pragma unroll
      for (int t = 0; t < TT; ++t) {
        const float d = Df[t * 256 + (tid ^ (((t >> 2) & 3) << 4))] + bbh;
        c_s = fmaf(beta, c_s, omb * d);
        m_s = fmaf(alpha, m_s, oma * c_s);
        *(unsigned short*)(&Mb[(t * 256 + (tid ^ ((t & 7) << 3))) * 2]) = f2bf(m_s);
      }
    }

    __syncthreads();  // B2: M ready AND next X staged

    // ---- projection: wave = rows [16tp..+16), k slice [64hp..+64) ----
    f32x4 p = f32x4{0.f, 0.f, 0.f, 0.f};
    {
      const int trow = 16 * tp + l16;
      #pragma unroll
      for (int ks = 0; ks < 2; ++ks) {
        const int h0 = 64 * hp + 32 * ks + 8 * lhi;
        Frag ma;
        ma.u = *(const u32x4*)(&Mb[(trow * 256 + (h0 ^ ((trow & 7) << 3))) * 2]);
        p = __builtin_amdgcn_mfma_f32_16x16x32_bf16(ma.b, WoF[ks].b, p, 0, 0, 0);
      }
    }
    #pragma unroll
    for (int r = 0; r < 4; ++r)
      Plds[tp][hp][4 * lhi + r][l16] = p[r];

    __syncthreads();  // B3: partials ready

    // ---- reduce + bias + sigmoid + store (threads 0..511) ----
    if (tid < 512) {
      const int trow = tid >> 3, j = tid & 7;
      const int t16 = trow & 15, ts = trow >> 4;
      const float sum = Plds[ts][0][t16][j] + Plds[ts][1][t16][j] +
                        Plds[ts][2][t16][j] + Plds[ts][3][t16][j] + bo_j;
      outb[(size_t)(kt * TT + trow) * OUTt + j] = 1.f / (1.f + __expf(-sum));
    }
    // no trailing barrier needed: next tile's Plds writes are 2 barriers away
  }
}

extern "C" void kernel_launch(void* const* d_in, const int* in_sizes, int n_in,
                              void* d_out, int out_size, void* d_ws, size_t ws_size,
                              hipStream_t stream) {
  const float* x     = (const float*)d_in[0];
  const float* Wb    = (const float*)d_in[1];
  const float* bb    = (const float*)d_in[2];
  const float* Wo    = (const float*)d_in[3];
  const float* bo    = (const float*)d_in[4];
  const float* tau_m = (const float*)d_in[5];
  const float* tau_n = (const float*)d_in[6];
  float* out = (float*)d_out;

  sfnn_fused<<<dim3(256), dim3(1024), 0, stream>>>(x, Wb, bb, Wo, bo, tau_m, tau_n, out);
}